// Round 1
// baseline (1126.411 us; speedup 1.0000x reference)
//
#include <hip/hip_runtime.h>

#define C_CH   64
#define H_IN   200
#define W_IN   320
#define H_OUT  48
#define W_OUT  320
#define N_BOX  256

// Direct-gather version: no LDS, no barrier.
// One block per (box, channel); 320 threads; thread t = output column j.
// col mapping is monotone with step <= 1 across lanes, so each wave-load
// touches a <=256B contiguous span of one input row (same-line lanes merge,
// duplicate-col lanes are free). Stores are perfectly coalesced 256B/wave
// nontemporal streams. __launch_bounds__(320,8) forces <=64 VGPR so the CU
// holds ~30 waves (vs 10 with the 61KB LDS tile) — latency hiding via TLP.
__global__ __launch_bounds__(320, 8) void roi_crop_kernel(
    const float* __restrict__ x,
    const int*   __restrict__ bboxes,
    const int*   __restrict__ box_img,
    float*       __restrict__ out)
{
    const int box = blockIdx.x;   // box     0..255  (fastest -> same-image boxes co-resident, L2 reuse)
    const int c   = blockIdx.y;   // channel 0..63
    const int t   = threadIdx.x;  // output column j = 0..319

    int x0 = bboxes[box * 4 + 0];
    int y0 = bboxes[box * 4 + 1];
    int x1 = bboxes[box * 4 + 2];
    int y1 = bboxes[box * 4 + 3];

    x0 = min(max(x0, 0), W_IN - 1);
    y0 = min(max(y0, 0), H_IN - 1);
    x1 = min(max(x1, 0), W_IN - 1);
    y1 = min(max(y1, 0), H_IN - 1);
    x1 = max(x1, x0);
    y1 = max(y1, y0);

    const int h   = y1 - y0 + 1;
    const int w   = x1 - x0 + 1;
    const int img = box_img[box];

    const float* __restrict__ plane_in =
        x + ((size_t)img * C_CH + c) * (H_IN * W_IN);
    float* __restrict__ plane_out =
        out + ((size_t)box * C_CH + c) * (H_OUT * W_OUT);

    const int col = x0 + (t * w) / W_OUT;     // per-lane, step <= 1
    const float* __restrict__ src = plane_in + col;
    float*       __restrict__ dst = plane_out + t;

    #pragma unroll 8
    for (int i = 0; i < H_OUT; ++i) {
        const int r = y0 + (i * h) / H_OUT;   // block-uniform -> scalar path
        const float val = src[r * W_IN];      // gather: L1/L2-served, <=256B span/wave
        __builtin_nontemporal_store(val, dst + i * W_OUT);
    }
}

extern "C" void kernel_launch(void* const* d_in, const int* in_sizes, int n_in,
                              void* d_out, int out_size, void* d_ws, size_t ws_size,
                              hipStream_t stream) {
    const float* x       = (const float*)d_in[0];
    const int*   bboxes  = (const int*)d_in[1];
    const int*   box_img = (const int*)d_in[2];
    float*       out     = (float*)d_out;

    dim3 grid(N_BOX, C_CH);   // (256, 64) = 16384 blocks
    dim3 block(320);
    roi_crop_kernel<<<grid, block, 0, stream>>>(x, bboxes, box_img, out);
}

// Round 2
// 1113.277 us; speedup vs baseline: 1.0118x; 1.0118x over previous
//
#include <hip/hip_runtime.h>
#include <stdint.h>

#define C_CH   64
#define H_IN   200
#define W_IN   320
#define H_OUT  48
#define W_OUT  320
#define N_BOX  256
#define CHUNK  8
#define NCHUNK (H_OUT / CHUNK)   // 6

// Chunked, double-buffered LDS staging with async global->LDS (width 16) and
// counted vmcnt waits. One block per (box, channel), 320 threads (5 waves).
//
// Per chunk (8 rows x 320 cols = 10,240 B): each wave issues exactly 2
// global_load_lds_dwordx4 ops (64 lanes x 16 B = 1024 B each; 5 waves x 2 x
// 1024 B = 10,240 B). LDS layout is linear in lane order (wave-uniform base +
// lane*16) which matches the [8][320] row-major chunk exactly.
//
// Per-wave vmem FIFO per iteration is [2 glds, 8 nt-stores], so the counted
// waits are: k=0 -> vmcnt(2); steady-state -> vmcnt(10) (allow next chunk's 2
// glds + prev chunk's 8 stores); last -> vmcnt(8). Never vmcnt(0) in the loop.
// sched_barrier(0) fences prevent the compiler from moving any memory op
// across the wait/barrier points (which would invalidate the FIFO counts).
//
// LDS/block = 2*8*320*4 = 20,480 B -> 6 blocks/CU (30 waves, wave-limited)
// vs 2 blocks/CU for the monolithic 61,440 B tile.

typedef __attribute__((address_space(3))) void       lds_vp;
typedef __attribute__((address_space(1))) const void gbl_vp;

__device__ __forceinline__ void glds16(const float* g, float* l) {
    __builtin_amdgcn_global_load_lds((gbl_vp*)g, (lds_vp*)l, 16, 0, 0);
}

__global__ __launch_bounds__(320) void roi_crop_kernel(
    const float* __restrict__ x,
    const int*   __restrict__ bboxes,
    const int*   __restrict__ box_img,
    float*       __restrict__ out)
{
    __shared__ __align__(16) float tile[2][CHUNK * W_OUT];   // 2 x 10,240 B

    const int box = blockIdx.x;   // box     0..255 (fastest: same-img boxes co-resident)
    const int c   = blockIdx.y;   // channel 0..63
    const int t   = threadIdx.x;  // 0..319

    const int4 bb = *(const int4*)(bboxes + box * 4);   // uniform -> s_load_dwordx4
    int x0 = min(max(bb.x, 0), W_IN - 1);
    int y0 = min(max(bb.y, 0), H_IN - 1);
    int x1 = min(max(bb.z, 0), W_IN - 1);
    int y1 = min(max(bb.w, 0), H_IN - 1);
    x1 = max(x1, x0);
    y1 = max(y1, y0);

    const int h   = y1 - y0 + 1;
    const int w   = x1 - x0 + 1;
    const int img = box_img[box];

    const float* __restrict__ plane_in =
        x + ((size_t)img * C_CH + c) * (H_IN * W_IN);
    float* __restrict__ plane_out =
        out + ((size_t)box * C_CH + c) * (H_OUT * W_OUT);

    const int wave  = t >> 6;
    const int lane  = t & 63;
    const int pbase = wave * 2048 + lane * 16;      // byte offset within chunk
    const int col   = x0 + (t * w) / W_OUT;         // lane step <= 1 -> conflict-free LDS reads

    // Issue the 2 async stages for chunk k into buffer nb.
    auto stage = [&](int k, int nb) {
        #pragma unroll
        for (int q = 0; q < 2; ++q) {
            const int p   = pbase + (q << 10);      // 0..10239
            const int rl  = p / 1280;               // local row 0..7 (const-div)
            const int off = p - rl * 1280;          // byte offset in row, 16B-mult
            const int r   = y0 + ((k * CHUNK + rl) * h) / H_OUT;
            glds16(plane_in + r * W_IN + (off >> 2),
                   &tile[nb][wave * 512 + (q << 8)]);
        }
    };

    stage(0, 0);
    __builtin_amdgcn_sched_barrier(0);

    #pragma unroll
    for (int k = 0; k < NCHUNK; ++k) {
        const int nb = k & 1;
        if (k + 1 < NCHUNK) stage(k + 1, nb ^ 1);
        __builtin_amdgcn_sched_barrier(0);
        if (k == 0)
            asm volatile("s_waitcnt vmcnt(2)" ::: "memory");
        else if (k + 1 < NCHUNK)
            asm volatile("s_waitcnt vmcnt(10)" ::: "memory");
        else
            asm volatile("s_waitcnt vmcnt(8)" ::: "memory");
        __builtin_amdgcn_sched_barrier(0);
        __builtin_amdgcn_s_barrier();               // chunk k resident in tile[nb]
        __builtin_amdgcn_sched_barrier(0);

        float* op = plane_out + (size_t)(k * CHUNK) * W_OUT + t;
        #pragma unroll
        for (int il = 0; il < CHUNK; ++il) {
            const float v = tile[nb][il * W_OUT + col];
            __builtin_nontemporal_store(v, op + il * W_OUT);
        }

        __builtin_amdgcn_sched_barrier(0);
        __builtin_amdgcn_s_barrier();               // all reads of tile[nb] done -> safe to overwrite
        __builtin_amdgcn_sched_barrier(0);
    }
}

extern "C" void kernel_launch(void* const* d_in, const int* in_sizes, int n_in,
                              void* d_out, int out_size, void* d_ws, size_t ws_size,
                              hipStream_t stream) {
    const float* x       = (const float*)d_in[0];
    const int*   bboxes  = (const int*)d_in[1];
    const int*   box_img = (const int*)d_in[2];
    float*       out     = (float*)d_out;

    dim3 grid(N_BOX, C_CH);   // (256, 64) = 16384 blocks
    dim3 block(320);
    roi_crop_kernel<<<grid, block, 0, stream>>>(x, bboxes, box_img, out);
}